// Round 2
// baseline (688.854 us; speedup 1.0000x reference)
//
#include <hip/hip_runtime.h>
#include <stdint.h>

typedef __attribute__((ext_vector_type(4))) float  f32x4;
typedef __attribute__((ext_vector_type(4))) short  short4v;
typedef __attribute__((ext_vector_type(8))) short  short8;
typedef __attribute__((ext_vector_type(8))) __bf16 bf16x8;

#define DEVI static __device__ __forceinline__

DEVI float bf2f_lo(uint32_t u) { union { uint32_t i; float f; } v; v.i = u << 16;          return v.f; }
DEVI float bf2f_hi(uint32_t u) { union { uint32_t i; float f; } v; v.i = u & 0xffff0000u;  return v.f; }
DEVI uint16_t f2bf(float f) {
    union { float f; uint32_t i; } v; v.f = f;
    uint32_t r = v.i + 0x7fffu + ((v.i >> 16) & 1u);
    return (uint16_t)(r >> 16);
}
DEVI void unpack8(uint4 u, float* f) {
    f[0] = bf2f_lo(u.x); f[1] = bf2f_hi(u.x);
    f[2] = bf2f_lo(u.y); f[3] = bf2f_hi(u.y);
    f[4] = bf2f_lo(u.z); f[5] = bf2f_hi(u.z);
    f[6] = bf2f_lo(u.w); f[7] = bf2f_hi(u.w);
}

// ---------------- weight prep: fp32 [K][N] -> bf16 [N][K] ----------------
__global__ __launch_bounds__(256) void wprep(const float* __restrict__ w,
                                             uint16_t* __restrict__ wt, int K, int N) {
    int idx = blockIdx.x * 256 + threadIdx.x;
    if (idx >= K * N) return;
    int k = idx / N, n = idx - k * N;
    wt[(size_t)n * K + k] = f2bf(w[idx]);
}

// ---------------- LayerNorm over C=256, write bf16 ----------------
__global__ __launch_bounds__(256) void ln_kernel(const float* __restrict__ x,
                                                 const float* __restrict__ g,
                                                 const float* __restrict__ be,
                                                 uint16_t* __restrict__ y) {
    int row  = blockIdx.x * 4 + (threadIdx.x >> 6);
    int lane = threadIdx.x & 63;
    const float* xr = x + (size_t)row * 256 + lane * 4;
    f32x4 v = *(const f32x4*)xr;
    float s  = v[0] + v[1] + v[2] + v[3];
    float s2 = v[0]*v[0] + v[1]*v[1] + v[2]*v[2] + v[3]*v[3];
#pragma unroll
    for (int off = 32; off > 0; off >>= 1) {
        s  += __shfl_xor(s, off);
        s2 += __shfl_xor(s2, off);
    }
    float mean = s * (1.f / 256.f);
    float var  = s2 * (1.f / 256.f) - mean * mean;
    float rs   = rsqrtf(var + 1e-5f);
    f32x4 gv = *(const f32x4*)(g  + lane * 4);
    f32x4 bv = *(const f32x4*)(be + lane * 4);
    uint64_t pk = 0;
#pragma unroll
    for (int j = 0; j < 4; ++j) {
        uint64_t b = f2bf((v[j] - mean) * rs * gv[j] + bv[j]);
        pk |= b << (16 * j);
    }
    *(uint64_t*)(y + (size_t)row * 256 + lane * 4) = pk;
}

// ---------------- GEMM: A[M][K] bf16  x  Bt[N][K] bf16 -> epilogue ----------------
// EPI 0: store bf16 raw;  1: +bias +resid -> fp32;  2: +bias, exact GELU -> bf16
template <int EPI>
__global__ __launch_bounds__(256) void gemm_bt(const uint16_t* __restrict__ A,
                                               const uint16_t* __restrict__ Bt,
                                               int M, int N, int K,
                                               const float* __restrict__ bias,
                                               const float* __restrict__ resid,
                                               void* __restrict__ outp) {
    __shared__ __align__(16) uint16_t As[128 * 32];
    __shared__ __align__(16) uint16_t Bs[128 * 32];
    const int tid  = threadIdx.x;
    const int lane = tid & 63;
    const int w    = tid >> 6;
    const int wr   = w >> 1, wc = w & 1;
    const int bm = blockIdx.x, bn = blockIdx.y;
    f32x4 acc[4][4] = {};
    const int nk = K >> 5;
    const int c0 = tid, c1 = tid + 256;

    for (int kk = 0; kk < nk; ++kk) {
        {
            const uint16_t* Ab = A  + (size_t)bm * 128 * K + kk * 32;
            const uint16_t* Bb = Bt + (size_t)bn * 128 * K + kk * 32;
            uint4 a0 = *(const uint4*)(Ab + (size_t)(c0 >> 2) * K + (c0 & 3) * 8);
            uint4 a1 = *(const uint4*)(Ab + (size_t)(c1 >> 2) * K + (c1 & 3) * 8);
            uint4 b0 = *(const uint4*)(Bb + (size_t)(c0 >> 2) * K + (c0 & 3) * 8);
            uint4 b1 = *(const uint4*)(Bb + (size_t)(c1 >> 2) * K + (c1 & 3) * 8);
            *(uint4*)&As[c0 * 8] = a0;
            *(uint4*)&As[c1 * 8] = a1;
            *(uint4*)&Bs[c0 * 8] = b0;
            *(uint4*)&Bs[c1 * 8] = b1;
        }
        __syncthreads();
        bf16x8 af[4], bfr[4];
        const int rA = wr * 64 + (lane & 15);
        const int rB = wc * 64 + (lane & 15);
        const int kb = (lane >> 4) * 4;
#pragma unroll
        for (int m = 0; m < 4; ++m) {
            short4v lo = *(const short4v*)&As[(rA + m * 16) * 32 + kb];
            short4v hi = *(const short4v*)&As[(rA + m * 16) * 32 + kb + 16];
            af[m] = __builtin_bit_cast(bf16x8,
                     __builtin_shufflevector(lo, hi, 0, 1, 2, 3, 4, 5, 6, 7));
        }
#pragma unroll
        for (int n = 0; n < 4; ++n) {
            short4v lo = *(const short4v*)&Bs[(rB + n * 16) * 32 + kb];
            short4v hi = *(const short4v*)&Bs[(rB + n * 16) * 32 + kb + 16];
            bfr[n] = __builtin_bit_cast(bf16x8,
                      __builtin_shufflevector(lo, hi, 0, 1, 2, 3, 4, 5, 6, 7));
        }
#pragma unroll
        for (int m = 0; m < 4; ++m)
#pragma unroll
            for (int n = 0; n < 4; ++n)
                acc[m][n] = __builtin_amdgcn_mfma_f32_16x16x32_bf16(af[m], bfr[n], acc[m][n], 0, 0, 0);
        __syncthreads();
    }

    const int row0 = bm * 128 + wr * 64 + ((lane >> 4) * 4);
    const int col0 = bn * 128 + wc * 64 + (lane & 15);
#pragma unroll
    for (int m = 0; m < 4; ++m) {
#pragma unroll
        for (int n = 0; n < 4; ++n) {
            const int col = col0 + n * 16;
#pragma unroll
            for (int r = 0; r < 4; ++r) {
                const int row = row0 + m * 16 + r;
                float v = acc[m][n][r];
                size_t idx = (size_t)row * N + col;
                if (EPI == 0) {
                    ((uint16_t*)outp)[idx] = f2bf(v);
                } else if (EPI == 1) {
                    ((float*)outp)[idx] = v + bias[col] + resid[idx];
                } else {
                    v += bias[col];
                    float ge = 0.5f * v * (1.0f + erff(v * 0.70710678118654752f));
                    ((uint16_t*)outp)[idx] = f2bf(ge);
                }
            }
        }
    }
}

// ---------------- cross-shaped window attention + LePE (vector flash) ----------------
// qkv: bf16 [25088][768] (q|k|v each 256ch). att out: bf16 [25088][256].
// branch 0: windows 56x7 (b, wcol in 0..7), heads 4, hd 32, channels 0..127
// branch 1: windows 7x56 (b, wrow in 0..7), channels 128..255
__global__ __launch_bounds__(64) void attn_kernel(const uint16_t* __restrict__ qkv,
                                                  const float* __restrict__ lw0,
                                                  const float* __restrict__ lb0,
                                                  const float* __restrict__ lw1,
                                                  const float* __restrict__ lb1,
                                                  uint16_t* __restrict__ att) {
    int bid = blockIdx.x;
    const int chunk = bid % 7;  bid /= 7;
    const int head  = bid & 3;  bid >>= 2;
    const int win   = bid & 63; bid >>= 6;
    const int branch = bid;
    const int lane = threadIdx.x;
    int l = chunk * 64 + lane;
    const bool active = (l < 392);
    if (!active) l = 391;
    const int b = win >> 3, wp = win & 7;

    int r, c;  // window-local coords
    if (branch == 0) { r = l / 7;  c = l % 7;  }
    else             { r = l / 56; c = l % 56; }
    int h, wcl;
    if (branch == 0) { h = r;          wcl = wp * 7 + c; }
    else             { h = wp * 7 + r; wcl = c;          }
    const int ch0 = branch * 128 + head * 32;
    const size_t tokbase = ((size_t)(b * 56 + h) * 56 + wcl);
    const float scale = 0.17677669529663687f;  // 1/sqrt(32)

    float qf[32];
    {
        const uint16_t* qp = qkv + tokbase * 768 + ch0;
#pragma unroll
        for (int i = 0; i < 4; ++i) {
            uint4 u = *(const uint4*)(qp + i * 8);
            float t[8]; unpack8(u, t);
#pragma unroll
            for (int j = 0; j < 8; ++j) qf[i * 8 + j] = t[j] * scale;
        }
    }

    float Mx = -1e30f, S = 0.f;
    float o[32];
#pragma unroll
    for (int d = 0; d < 32; ++d) o[d] = 0.f;

    int rm = 0, cm = 0;
    const int P = (branch == 0) ? 7 : 56;
    for (int m = 0; m < 392; ++m) {
        int hm, wmm;
        if (branch == 0) { hm = rm;          wmm = wp * 7 + cm; }
        else             { hm = wp * 7 + rm; wmm = cm;          }
        const uint16_t* kp = qkv + ((size_t)(b * 56 + hm) * 56 + wmm) * 768 + 256 + ch0;
        float kf[32], vf[32];
#pragma unroll
        for (int i = 0; i < 4; ++i) {
            uint4 uk = *(const uint4*)(kp + i * 8);
            unpack8(uk, &kf[i * 8]);
            uint4 uv = *(const uint4*)(kp + 256 + i * 8);
            unpack8(uv, &vf[i * 8]);
        }
        float s = 0.f;
#pragma unroll
        for (int d = 0; d < 32; ++d) s += qf[d] * kf[d];
        if (s > Mx + 8.f) {  // rare after first key (logits have small range)
            float corr = __expf(Mx - s);
            S *= corr;
#pragma unroll
            for (int d = 0; d < 32; ++d) o[d] *= corr;
            Mx = s;
        }
        float p = __expf(s - Mx);
        S += p;
#pragma unroll
        for (int d = 0; d < 32; ++d) o[d] += p * vf[d];
        if (++cm == P) { cm = 0; ++rm; }
    }
    float rn = 1.f / S;

    // LePE: depthwise 3x3 within the window on raw v, plus bias
    const float* lw = (branch == 0) ? lw0 : lw1;
    const float* lb = (branch == 0) ? lb0 : lb1;
    float lep[32];
#pragma unroll
    for (int d = 0; d < 32; ++d) lep[d] = lb[head * 32 + d];
    const int Hsp = (branch == 0) ? 56 : 7;
    const int Wsp = (branch == 0) ? 7 : 56;
    for (int dy = -1; dy <= 1; ++dy) {
        for (int dx = -1; dx <= 1; ++dx) {
            int rr = r + dy, cc = c + dx;
            if (rr < 0 || rr >= Hsp || cc < 0 || cc >= Wsp) continue;
            int h2, w2;
            if (branch == 0) { h2 = rr;          w2 = wp * 7 + cc; }
            else             { h2 = wp * 7 + rr; w2 = cc;          }
            const uint16_t* vp = qkv + ((size_t)(b * 56 + h2) * 56 + w2) * 768 + 512 + ch0;
            float vv[32];
#pragma unroll
            for (int i = 0; i < 4; ++i) {
                uint4 u = *(const uint4*)(vp + i * 8);
                unpack8(u, &vv[i * 8]);
            }
            const float* wrow = lw + (size_t)(head * 32) * 9 + (dy + 1) * 3 + (dx + 1);
#pragma unroll
            for (int d = 0; d < 32; ++d) lep[d] += vv[d] * wrow[(size_t)d * 9];
        }
    }

    if (active) {
        uint16_t ob[32];
#pragma unroll
        for (int d = 0; d < 32; ++d) ob[d] = f2bf(o[d] * rn + lep[d]);
        uint4* dst = (uint4*)(att + tokbase * 256 + ch0);
        const uint4* src = (const uint4*)ob;
#pragma unroll
        for (int i = 0; i < 4; ++i) dst[i] = src[i];
    }
}

// ---------------- launch ----------------
extern "C" void kernel_launch(void* const* d_in, const int* in_sizes, int n_in,
                              void* d_out, int out_size, void* d_ws, size_t ws_size,
                              hipStream_t stream) {
    const float* x      = (const float*)d_in[0];
    const float* g1     = (const float*)d_in[1];
    const float* be1    = (const float*)d_in[2];
    const float* w_qkv  = (const float*)d_in[3];
    const float* lw0    = (const float*)d_in[4];
    const float* lb0    = (const float*)d_in[5];
    const float* lw1    = (const float*)d_in[6];
    const float* lb1    = (const float*)d_in[7];
    const float* w_proj = (const float*)d_in[8];
    const float* b_proj = (const float*)d_in[9];
    const float* g2     = (const float*)d_in[10];
    const float* be2    = (const float*)d_in[11];
    const float* w_fc1  = (const float*)d_in[12];
    const float* b_fc1  = (const float*)d_in[13];
    const float* w_fc2  = (const float*)d_in[14];
    const float* b_fc2  = (const float*)d_in[15];
    float* out = (float*)d_out;

    char* p = (char*)d_ws;
    auto carve = [&](size_t bytes) -> char* {
        char* q = p; p += (bytes + 255) & ~(size_t)255; return q;
    };
    uint16_t* lnb    = (uint16_t*)carve((size_t)25088 * 256 * 2);   // ln1 then ln2
    uint16_t* qkvh   = (uint16_t*)carve((size_t)25088 * 1024 * 2);  // qkv then h
    uint16_t* attb   = (uint16_t*)carve((size_t)25088 * 256 * 2);
    float*    x1     = (float*)   carve((size_t)25088 * 256 * 4);
    uint16_t* wqkvT  = (uint16_t*)carve((size_t)768 * 256 * 2);
    uint16_t* wprojT = (uint16_t*)carve((size_t)256 * 256 * 2);
    uint16_t* wfc1T  = (uint16_t*)carve((size_t)1024 * 256 * 2);
    uint16_t* wfc2T  = (uint16_t*)carve((size_t)256 * 1024 * 2);

    wprep<<<768,  256, 0, stream>>>(w_qkv,  wqkvT,  256, 768);
    wprep<<<256,  256, 0, stream>>>(w_proj, wprojT, 256, 256);
    wprep<<<1024, 256, 0, stream>>>(w_fc1,  wfc1T,  256, 1024);
    wprep<<<1024, 256, 0, stream>>>(w_fc2,  wfc2T,  1024, 256);

    ln_kernel<<<6272, 256, 0, stream>>>(x, g1, be1, lnb);
    gemm_bt<0><<<dim3(196, 6), 256, 0, stream>>>(lnb, wqkvT, 25088, 768, 256,
                                                 nullptr, nullptr, qkvh);
    attn_kernel<<<3584, 64, 0, stream>>>(qkvh, lw0, lb0, lw1, lb1, attb);
    gemm_bt<1><<<dim3(196, 2), 256, 0, stream>>>(attb, wprojT, 25088, 256, 256,
                                                 b_proj, x, x1);
    ln_kernel<<<6272, 256, 0, stream>>>(x1, g2, be2, lnb);
    gemm_bt<2><<<dim3(196, 8), 256, 0, stream>>>(lnb, wfc1T, 25088, 1024, 256,
                                                 b_fc1, nullptr, qkvh);
    gemm_bt<1><<<dim3(196, 2), 256, 0, stream>>>(qkvh, wfc2T, 25088, 256, 1024,
                                                 b_fc2, x1, out);
}

// Round 4
// 501.649 us; speedup vs baseline: 1.3732x; 1.3732x over previous
//
#include <hip/hip_runtime.h>
#include <stdint.h>

typedef __attribute__((ext_vector_type(4))) float  f32x4;
typedef __attribute__((ext_vector_type(4))) short  short4v;
typedef __attribute__((ext_vector_type(8))) __bf16 bf16x8;

#define DEVI static __device__ __forceinline__

DEVI float bf2f_lo(uint32_t u) { union { uint32_t i; float f; } v; v.i = u << 16;          return v.f; }
DEVI float bf2f_hi(uint32_t u) { union { uint32_t i; float f; } v; v.i = u & 0xffff0000u;  return v.f; }
DEVI uint16_t f2bf(float f) {
    union { float f; uint32_t i; } v; v.f = f;
    uint32_t r = v.i + 0x7fffu + ((v.i >> 16) & 1u);
    return (uint16_t)(r >> 16);
}
DEVI void unpack8(uint4 u, float* f) {
    f[0] = bf2f_lo(u.x); f[1] = bf2f_hi(u.x);
    f[2] = bf2f_lo(u.y); f[3] = bf2f_hi(u.y);
    f[4] = bf2f_lo(u.z); f[5] = bf2f_hi(u.z);
    f[6] = bf2f_lo(u.w); f[7] = bf2f_hi(u.w);
}
DEVI void gload_lds16(const uint16_t* gp, uint16_t* lp) {
    __builtin_amdgcn_global_load_lds(
        (const __attribute__((address_space(1))) uint32_t*)gp,
        (__attribute__((address_space(3))) uint32_t*)lp, 16, 0, 0);
}

// ---------------- weight prep: fp32 [K][N] -> bf16 [N][K] ----------------
__global__ __launch_bounds__(256) void wprep(const float* __restrict__ w,
                                             uint16_t* __restrict__ wt, int K, int N) {
    int idx = blockIdx.x * 256 + threadIdx.x;
    if (idx >= K * N) return;
    int k = idx / N, n = idx - k * N;
    wt[(size_t)n * K + k] = f2bf(w[idx]);
}

// ---------------- LayerNorm over C=256, write bf16 ----------------
__global__ __launch_bounds__(256) void ln_kernel(const float* __restrict__ x,
                                                 const float* __restrict__ g,
                                                 const float* __restrict__ be,
                                                 uint16_t* __restrict__ y) {
    int row  = blockIdx.x * 4 + (threadIdx.x >> 6);
    int lane = threadIdx.x & 63;
    const float* xr = x + (size_t)row * 256 + lane * 4;
    f32x4 v = *(const f32x4*)xr;
    float s  = v[0] + v[1] + v[2] + v[3];
    float s2 = v[0]*v[0] + v[1]*v[1] + v[2]*v[2] + v[3]*v[3];
#pragma unroll
    for (int off = 32; off > 0; off >>= 1) {
        s  += __shfl_xor(s, off);
        s2 += __shfl_xor(s2, off);
    }
    float mean = s * (1.f / 256.f);
    float var  = s2 * (1.f / 256.f) - mean * mean;
    float rs   = rsqrtf(var + 1e-5f);
    f32x4 gv = *(const f32x4*)(g  + lane * 4);
    f32x4 bv = *(const f32x4*)(be + lane * 4);
    uint64_t pk = 0;
#pragma unroll
    for (int j = 0; j < 4; ++j) {
        uint64_t b = f2bf((v[j] - mean) * rs * gv[j] + bv[j]);
        pk |= b << (16 * j);
    }
    *(uint64_t*)(y + (size_t)row * 256 + lane * 4) = pk;
}

// ---------------- GEMM: A[M][K] bf16  x  Bt[N][K] bf16 -> epilogue ----------------
// EPI 0: store bf16 raw;  1: +bias +resid -> fp32;  2: +bias, exact GELU -> bf16
template <int EPI>
__global__ __launch_bounds__(256) void gemm_bt(const uint16_t* __restrict__ A,
                                               const uint16_t* __restrict__ Bt,
                                               int M, int N, int K,
                                               const float* __restrict__ bias,
                                               const float* __restrict__ resid,
                                               void* __restrict__ outp) {
    __shared__ __align__(16) uint16_t As[128 * 32];
    __shared__ __align__(16) uint16_t Bs[128 * 32];
    const int tid  = threadIdx.x;
    const int lane = tid & 63;
    const int w    = tid >> 6;
    const int wr   = w >> 1, wc = w & 1;
    const int bm = blockIdx.x, bn = blockIdx.y;
    f32x4 acc[4][4] = {};
    const int nk = K >> 5;
    const int c0 = tid, c1 = tid + 256;
    const int wb = (tid >> 6) * 512;   // wave-uniform LDS base (halves)

    for (int kk = 0; kk < nk; ++kk) {
        {
            const uint16_t* Ab = A  + (size_t)bm * 128 * K + kk * 32;
            const uint16_t* Bb = Bt + (size_t)bn * 128 * K + kk * 32;
            gload_lds16(Ab + (size_t)(c0 >> 2) * K + (c0 & 3) * 8, &As[wb]);
            gload_lds16(Ab + (size_t)(c1 >> 2) * K + (c1 & 3) * 8, &As[wb + 2048]);
            gload_lds16(Bb + (size_t)(c0 >> 2) * K + (c0 & 3) * 8, &Bs[wb]);
            gload_lds16(Bb + (size_t)(c1 >> 2) * K + (c1 & 3) * 8, &Bs[wb + 2048]);
        }
        __syncthreads();
        bf16x8 af[4], bfr[4];
        const int rA = wr * 64 + (lane & 15);
        const int rB = wc * 64 + (lane & 15);
        const int kb = (lane >> 4) * 4;
#pragma unroll
        for (int m = 0; m < 4; ++m) {
            short4v lo = *(const short4v*)&As[(rA + m * 16) * 32 + kb];
            short4v hi = *(const short4v*)&As[(rA + m * 16) * 32 + kb + 16];
            af[m] = __builtin_bit_cast(bf16x8,
                     __builtin_shufflevector(lo, hi, 0, 1, 2, 3, 4, 5, 6, 7));
        }
#pragma unroll
        for (int n = 0; n < 4; ++n) {
            short4v lo = *(const short4v*)&Bs[(rB + n * 16) * 32 + kb];
            short4v hi = *(const short4v*)&Bs[(rB + n * 16) * 32 + kb + 16];
            bfr[n] = __builtin_bit_cast(bf16x8,
                      __builtin_shufflevector(lo, hi, 0, 1, 2, 3, 4, 5, 6, 7));
        }
#pragma unroll
        for (int m = 0; m < 4; ++m)
#pragma unroll
            for (int n = 0; n < 4; ++n)
                acc[m][n] = __builtin_amdgcn_mfma_f32_16x16x32_bf16(af[m], bfr[n], acc[m][n], 0, 0, 0);
        __syncthreads();
    }

    const int row0 = bm * 128 + wr * 64 + ((lane >> 4) * 4);
    const int col0 = bn * 128 + wc * 64 + (lane & 15);
#pragma unroll
    for (int m = 0; m < 4; ++m) {
#pragma unroll
        for (int n = 0; n < 4; ++n) {
            const int col = col0 + n * 16;
#pragma unroll
            for (int r = 0; r < 4; ++r) {
                const int row = row0 + m * 16 + r;
                float v = acc[m][n][r];
                size_t idx = (size_t)row * N + col;
                if (EPI == 0) {
                    ((uint16_t*)outp)[idx] = f2bf(v);
                } else if (EPI == 1) {
                    ((float*)outp)[idx] = v + bias[col] + resid[idx];
                } else {
                    v += bias[col];
                    float ge = 0.5f * v * (1.0f + erff(v * 0.70710678118654752f));
                    ((uint16_t*)outp)[idx] = f2bf(ge);
                }
            }
        }
    }
}

// ---------------- MFMA cross-shaped window attention (swapped QK^T) ----------------
// block = (branch, win, head, qtile); 1 wave. S^T = mfma(K,Q); PV as O^T = mfma(V^T,P^T).
// C/D layout (HW-verified): col = lane&15, row = (lane>>4)*4 + reg.
__global__ __launch_bounds__(64) void attn_mfma(const uint16_t* __restrict__ qkv,
                                                uint16_t* __restrict__ att) {
    __shared__ __align__(16) uint16_t Pl[64 * 40];  // P [64 q][40 halves] (pad 32->40)
    int bid = blockIdx.x;
    const int qtile = bid % 7;  bid /= 7;
    const int head  = bid & 3;  bid >>= 2;
    const int win   = bid & 63; bid >>= 6;
    const int branch = bid;
    const int lane = threadIdx.x;
    const int g  = lane >> 4;
    const int li = lane & 15;
    const int b = win >> 3, wp = win & 7;
    const int ch0 = branch * 128 + head * 32;
    const int base0 = b * 3136;
    const int woff  = wp * 7;
    const int toks1 = base0 + wp * 392;

    auto tokof = [&](int l) -> int {
        if (branch == 0) { int r = l / 7; return base0 + r * 56 + woff + (l - r * 7); }
        return toks1 + l;
    };
    const int tok391 = tokof(391);
    const int q0 = qtile * 64;

    // Q B-frags: n=q=li+16nb, k-slot j -> ch g*8+j
    bf16x8 qf[4];
#pragma unroll
    for (int nb = 0; nb < 4; ++nb) {
        int ql = q0 + nb * 16 + li; if (ql > 391) ql = 391;
        qf[nb] = __builtin_bit_cast(bf16x8,
                 *(const uint4*)(qkv + (size_t)tokof(ql) * 768 + ch0 + g * 8));
    }

    float m_run[4], s_run[4];
    f32x4 oacc[2][4];
#pragma unroll
    for (int nb = 0; nb < 4; ++nb) {
        m_run[nb] = -1e30f; s_run[nb] = 0.f;
        oacc[0][nb] = (f32x4)0.f; oacc[1][nb] = (f32x4)0.f;
    }
    const float scale = 0.17677669529663687f;  // 1/sqrt(32)

    for (int kt = 0; kt < 13; ++kt) {
        const int kbase = kt * 32;
        // K A-frags: m=key=li+16mb, k-slot j -> ch g*8+j
        bf16x8 kf[2];
#pragma unroll
        for (int mb = 0; mb < 2; ++mb) {
            int kl = kbase + mb * 16 + li; if (kl > 391) kl = 391;
            kf[mb] = __builtin_bit_cast(bf16x8,
                     *(const uint4*)(qkv + (size_t)tokof(kl) * 768 + 256 + ch0 + g * 8));
        }
        // V gathers (issued early; A-frags for PV): lane ch=li(+16mb), keys g*8..+7
        uint16_t vg0[8], vg1[8];
        {
            int kl0 = kbase + g * 8;
            int tk, cc = 0;
            if (branch == 0) { int r = kl0 / 7; cc = kl0 - r * 7; tk = base0 + r * 56 + woff + cc; }
            else tk = toks1 + kl0;
#pragma unroll
            for (int j = 0; j < 8; ++j) {
                int t = (kl0 + j > 391) ? tok391 : tk;
                const uint16_t* vp = qkv + (size_t)t * 768 + 512 + ch0 + li;
                vg0[j] = vp[0];
                vg1[j] = vp[16];
                if (branch == 0) { if (++cc == 7) { cc = 0; tk += 50; } else ++tk; }
                else ++tk;
            }
        }
        // S^T[key][q]
        f32x4 sa[2][4] = {};
#pragma unroll
        for (int mb = 0; mb < 2; ++mb)
#pragma unroll
            for (int nb = 0; nb < 4; ++nb)
                sa[mb][nb] = __builtin_amdgcn_mfma_f32_16x16x32_bf16(kf[mb], qf[nb], sa[mb][nb], 0, 0, 0);
#pragma unroll
        for (int mb = 0; mb < 2; ++mb)
#pragma unroll
            for (int nb = 0; nb < 4; ++nb)
#pragma unroll
                for (int r = 0; r < 4; ++r) sa[mb][nb][r] *= scale;
        if (kt == 12) {  // keys valid iff kbase + mb*16 + g*4 + r < 392 -> mb==0 && g<2
#pragma unroll
            for (int nb = 0; nb < 4; ++nb)
#pragma unroll
                for (int r = 0; r < 4; ++r) {
                    if (g >= 2) sa[0][nb][r] = -1e30f;
                    sa[1][nb][r] = -1e30f;
                }
        }
        // online softmax per q-col
#pragma unroll
        for (int nb = 0; nb < 4; ++nb) {
            f32x4 mx = sa[0][nb];
#pragma unroll
            for (int r = 0; r < 4; ++r) mx[r] = fmaxf(mx[r], sa[1][nb][r]);
            float mt = fmaxf(fmaxf(mx[0], mx[1]), fmaxf(mx[2], mx[3]));
            mt = fmaxf(mt, __shfl_xor(mt, 16));
            mt = fmaxf(mt, __shfl_xor(mt, 32));
            float m_new = fmaxf(m_run[nb], mt);
            float corr = __expf(m_run[nb] - m_new);
            m_run[nb] = m_new;
#pragma unroll
            for (int mb = 0; mb < 2; ++mb)
#pragma unroll
                for (int r = 0; r < 4; ++r) oacc[mb][nb][r] *= corr;
            float psum = 0.f;
            uint32_t pk[4];
#pragma unroll
            for (int mb = 0; mb < 2; ++mb) {
                float p0 = __expf(sa[mb][nb][0] - m_new);
                float p1 = __expf(sa[mb][nb][1] - m_new);
                float p2 = __expf(sa[mb][nb][2] - m_new);
                float p3 = __expf(sa[mb][nb][3] - m_new);
                psum += (p0 + p1) + (p2 + p3);
                pk[mb * 2 + 0] = (uint32_t)f2bf(p0) | ((uint32_t)f2bf(p1) << 16);
                pk[mb * 2 + 1] = (uint32_t)f2bf(p2) | ((uint32_t)f2bf(p3) << 16);
            }
            psum += __shfl_xor(psum, 16);
            psum += __shfl_xor(psum, 32);
            s_run[nb] = s_run[nb] * corr + psum;
            // write P[q][key]: q = li+16nb, keys g*4+16mb (+0,1 / +2,3)
            uint32_t* dst = (uint32_t*)&Pl[(li + 16 * nb) * 40];
            dst[g * 2 + 0] = pk[0];
            dst[g * 2 + 1] = pk[1];
            dst[g * 2 + 8] = pk[2];
            dst[g * 2 + 9] = pk[3];
        }
        // PV: O^T += V^T * P^T
        union { uint16_t u[8]; bf16x8 v; } cv0, cv1;
#pragma unroll
        for (int j = 0; j < 8; ++j) { cv0.u[j] = vg0[j]; cv1.u[j] = vg1[j]; }
        bf16x8 vf0 = cv0.v, vf1 = cv1.v;
        bf16x8 pf[4];
#pragma unroll
        for (int nb = 0; nb < 4; ++nb)
            pf[nb] = __builtin_bit_cast(bf16x8,
                     *(const uint4*)&Pl[(li + 16 * nb) * 40 + g * 8]);
#pragma unroll
        for (int nb = 0; nb < 4; ++nb) {
            oacc[0][nb] = __builtin_amdgcn_mfma_f32_16x16x32_bf16(vf0, pf[nb], oacc[0][nb], 0, 0, 0);
            oacc[1][nb] = __builtin_amdgcn_mfma_f32_16x16x32_bf16(vf1, pf[nb], oacc[1][nb], 0, 0, 0);
        }
    }
    // epilogue: O^T row = ch = g*4+r+16mb, col = q = li+16nb
#pragma unroll
    for (int nb = 0; nb < 4; ++nb) {
        int ql = q0 + nb * 16 + li;
        if (ql <= 391) {
            float rn = 1.f / s_run[nb];
            uint16_t* op = att + (size_t)tokof(ql) * 256 + ch0;
#pragma unroll
            for (int mb = 0; mb < 2; ++mb)
#pragma unroll
                for (int r = 0; r < 4; ++r)
                    op[mb * 16 + g * 4 + r] = f2bf(oacc[mb][nb][r] * rn);
        }
    }
}

// ---------------- LePE: att += depthwise 3x3 conv(V) + bias (RMW) ----------------
__global__ __launch_bounds__(256) void lepe_kernel(const uint16_t* __restrict__ qkv,
                                                   const float* __restrict__ lw0,
                                                   const float* __restrict__ lb0,
                                                   const float* __restrict__ lw1,
                                                   const float* __restrict__ lb1,
                                                   uint16_t* __restrict__ att) {
    int idx = blockIdx.x * 256 + threadIdx.x;   // 25088*32
    int t = idx >> 5, cg = idx & 31;
    int ch = cg * 8;
    int branch = ch >> 7;
    int chb = ch & 127;
    int b = t / 3136, rem = t - b * 3136, h = rem / 56, w = rem - h * 56;
    const float* lw = branch ? lw1 : lw0;
    const float* lb = branch ? lb1 : lb0;
    float acc[8];
#pragma unroll
    for (int d = 0; d < 8; ++d) acc[d] = lb[chb + d];
    int r0, r1, c0, c1;
    if (branch == 0) { r0 = 0; r1 = 55; int wp = w / 7; c0 = wp * 7; c1 = c0 + 6; }
    else             { int hp = h / 7; r0 = hp * 7; r1 = r0 + 6; c0 = 0; c1 = 55; }
    for (int dy = -1; dy <= 1; ++dy) {
        for (int dx = -1; dx <= 1; ++dx) {
            int hh = h + dy, ww = w + dx;
            if (hh < r0 || hh > r1 || ww < c0 || ww > c1) continue;
            const uint16_t* vp = qkv + ((size_t)(b * 3136 + hh * 56 + ww)) * 768 + 512 + ch;
            uint4 u = *(const uint4*)vp;
            float vv[8]; unpack8(u, vv);
#pragma unroll
            for (int d = 0; d < 8; ++d)
                acc[d] += vv[d] * lw[(size_t)(chb + d) * 9 + (dy + 1) * 3 + (dx + 1)];
        }
    }
    uint16_t* ap = att + (size_t)t * 256 + ch;
    uint4 a = *(const uint4*)ap;
    float av[8]; unpack8(a, av);
    uint16_t ob[8];
#pragma unroll
    for (int d = 0; d < 8; ++d) ob[d] = f2bf(av[d] + acc[d]);
    *(uint4*)ap = *(const uint4*)ob;
}

// ---------------- launch ----------------
extern "C" void kernel_launch(void* const* d_in, const int* in_sizes, int n_in,
                              void* d_out, int out_size, void* d_ws, size_t ws_size,
                              hipStream_t stream) {
    const float* x      = (const float*)d_in[0];
    const float* g1     = (const float*)d_in[1];
    const float* be1    = (const float*)d_in[2];
    const float* w_qkv  = (const float*)d_in[3];
    const float* lw0    = (const float*)d_in[4];
    const float* lb0    = (const float*)d_in[5];
    const float* lw1    = (const float*)d_in[6];
    const float* lb1    = (const float*)d_in[7];
    const float* w_proj = (const float*)d_in[8];
    const float* b_proj = (const float*)d_in[9];
    const float* g2     = (const float*)d_in[10];
    const float* be2    = (const float*)d_in[11];
    const float* w_fc1  = (const float*)d_in[12];
    const float* b_fc1  = (const float*)d_in[13];
    const float* w_fc2  = (const float*)d_in[14];
    const float* b_fc2  = (const float*)d_in[15];
    float* out = (float*)d_out;

    char* p = (char*)d_ws;
    auto carve = [&](size_t bytes) -> char* {
        char* q = p; p += (bytes + 255) & ~(size_t)255; return q;
    };
    uint16_t* lnb    = (uint16_t*)carve((size_t)25088 * 256 * 2);   // ln1 then ln2
    uint16_t* qkvh   = (uint16_t*)carve((size_t)25088 * 1024 * 2);  // qkv then h
    uint16_t* attb   = (uint16_t*)carve((size_t)25088 * 256 * 2);
    float*    x1     = (float*)   carve((size_t)25088 * 256 * 4);
    uint16_t* wqkvT  = (uint16_t*)carve((size_t)768 * 256 * 2);
    uint16_t* wprojT = (uint16_t*)carve((size_t)256 * 256 * 2);
    uint16_t* wfc1T  = (uint16_t*)carve((size_t)1024 * 256 * 2);
    uint16_t* wfc2T  = (uint16_t*)carve((size_t)256 * 1024 * 2);

    wprep<<<768,  256, 0, stream>>>(w_qkv,  wqkvT,  256, 768);
    wprep<<<256,  256, 0, stream>>>(w_proj, wprojT, 256, 256);
    wprep<<<1024, 256, 0, stream>>>(w_fc1,  wfc1T,  256, 1024);
    wprep<<<1024, 256, 0, stream>>>(w_fc2,  wfc2T,  1024, 256);

    ln_kernel<<<6272, 256, 0, stream>>>(x, g1, be1, lnb);
    gemm_bt<0><<<dim3(196, 6), 256, 0, stream>>>(lnb, wqkvT, 25088, 768, 256,
                                                 nullptr, nullptr, qkvh);
    attn_mfma<<<3584, 64, 0, stream>>>(qkvh, attb);
    lepe_kernel<<<3136, 256, 0, stream>>>(qkvh, lw0, lb0, lw1, lb1, attb);
    gemm_bt<1><<<dim3(196, 2), 256, 0, stream>>>(attb, wprojT, 25088, 256, 256,
                                                 b_proj, x, x1);
    ln_kernel<<<6272, 256, 0, stream>>>(x1, g2, be2, lnb);
    gemm_bt<2><<<dim3(196, 8), 256, 0, stream>>>(lnb, wfc1T, 25088, 1024, 256,
                                                 b_fc1, nullptr, qkvh);
    gemm_bt<1><<<dim3(196, 2), 256, 0, stream>>>(qkvh, wfc2T, 25088, 256, 1024,
                                                 b_fc2, x1, out);
}

// Round 6
// 390.717 us; speedup vs baseline: 1.7631x; 1.2839x over previous
//
#include <hip/hip_runtime.h>
#include <stdint.h>

typedef __attribute__((ext_vector_type(4))) float  f32x4;
typedef __attribute__((ext_vector_type(4))) short  short4v;
typedef __attribute__((ext_vector_type(8))) __bf16 bf16x8;

#define DEVI static __device__ __forceinline__

DEVI float bf2f_lo(uint32_t u) { union { uint32_t i; float f; } v; v.i = u << 16;          return v.f; }
DEVI float bf2f_hi(uint32_t u) { union { uint32_t i; float f; } v; v.i = u & 0xffff0000u;  return v.f; }
DEVI uint16_t f2bf(float f) {
    union { float f; uint32_t i; } v; v.f = f;
    uint32_t r = v.i + 0x7fffu + ((v.i >> 16) & 1u);
    return (uint16_t)(r >> 16);
}
DEVI void unpack8(uint4 u, float* f) {
    f[0] = bf2f_lo(u.x); f[1] = bf2f_hi(u.x);
    f[2] = bf2f_lo(u.y); f[3] = bf2f_hi(u.y);
    f[4] = bf2f_lo(u.z); f[5] = bf2f_hi(u.z);
    f[6] = bf2f_lo(u.w); f[7] = bf2f_hi(u.w);
}
DEVI void gload_lds16(const uint16_t* gp, uint16_t* lp) {
    __builtin_amdgcn_global_load_lds(
        (const __attribute__((address_space(1))) uint32_t*)gp,
        (__attribute__((address_space(3))) uint32_t*)lp, 16, 0, 0);
}

// ---------------- weight prep: fp32 [K][N] -> bf16 [N][K] ----------------
__global__ __launch_bounds__(256) void wprep(const float* __restrict__ w,
                                             uint16_t* __restrict__ wt, int K, int N) {
    int idx = blockIdx.x * 256 + threadIdx.x;
    if (idx >= K * N) return;
    int k = idx / N, n = idx - k * N;
    wt[(size_t)n * K + k] = f2bf(w[idx]);
}

// ---------------- LayerNorm over C=256, write bf16 ----------------
__global__ __launch_bounds__(256) void ln_kernel(const float* __restrict__ x,
                                                 const float* __restrict__ g,
                                                 const float* __restrict__ be,
                                                 uint16_t* __restrict__ y) {
    int row  = blockIdx.x * 4 + (threadIdx.x >> 6);
    int lane = threadIdx.x & 63;
    const float* xr = x + (size_t)row * 256 + lane * 4;
    f32x4 v = *(const f32x4*)xr;
    float s  = v[0] + v[1] + v[2] + v[3];
    float s2 = v[0]*v[0] + v[1]*v[1] + v[2]*v[2] + v[3]*v[3];
#pragma unroll
    for (int off = 32; off > 0; off >>= 1) {
        s  += __shfl_xor(s, off);
        s2 += __shfl_xor(s2, off);
    }
    float mean = s * (1.f / 256.f);
    float var  = s2 * (1.f / 256.f) - mean * mean;
    float rs   = rsqrtf(var + 1e-5f);
    f32x4 gv = *(const f32x4*)(g  + lane * 4);
    f32x4 bv = *(const f32x4*)(be + lane * 4);
    uint64_t pk = 0;
#pragma unroll
    for (int j = 0; j < 4; ++j) {
        uint64_t b = f2bf((v[j] - mean) * rs * gv[j] + bv[j]);
        pk |= b << (16 * j);
    }
    *(uint64_t*)(y + (size_t)row * 256 + lane * 4) = pk;
}

// ---------------- GEMM: A[M][K] bf16  x  Bt[N][K] bf16 -> epilogue ----------------
// T3-minimum 2-phase: issue next tile's global_load_lds BEFORE computing current
// tile; single __syncthreads per tile (compiler-owned vmcnt/lgkmcnt drain + barrier)
// hides the staging latency under ds_read+MFMA. No inline asm (round-5 raced).
// EPI 0: store bf16 raw;  1: +bias +resid -> fp32;  2: +bias, exact GELU -> bf16
template <int EPI>
__global__ __launch_bounds__(256) void gemm_bt(const uint16_t* __restrict__ A,
                                               const uint16_t* __restrict__ Bt,
                                               int M, int N, int K,
                                               const float* __restrict__ bias,
                                               const float* __restrict__ resid,
                                               void* __restrict__ outp) {
    __shared__ __align__(16) uint16_t As[2][128 * 32];
    __shared__ __align__(16) uint16_t Bs[2][128 * 32];
    const int tid  = threadIdx.x;
    const int lane = tid & 63;
    const int w    = tid >> 6;
    const int wr   = w >> 1, wc = w & 1;
    const int bm = blockIdx.x, bn = blockIdx.y;
    f32x4 acc[4][4] = {};
    const int nk = K >> 5;
    const int c0 = tid, c1 = tid + 256;
    const int wb = (tid >> 6) * 512;   // wave-uniform LDS base (halves)

    const uint16_t* Abase = A  + (size_t)bm * 128 * K;
    const uint16_t* Bbase = Bt + (size_t)bn * 128 * K;
    const size_t ao0 = (size_t)(c0 >> 2) * K + (c0 & 3) * 8;
    const size_t ao1 = (size_t)(c1 >> 2) * K + (c1 & 3) * 8;

    auto stage = [&](int buf, int kk) {
        const uint16_t* Ab = Abase + kk * 32;
        const uint16_t* Bb = Bbase + kk * 32;
        gload_lds16(Ab + ao0, &As[buf][wb]);
        gload_lds16(Ab + ao1, &As[buf][wb + 2048]);
        gload_lds16(Bb + ao0, &Bs[buf][wb]);
        gload_lds16(Bb + ao1, &Bs[buf][wb + 2048]);
    };

    stage(0, 0);
    __syncthreads();               // tile 0 fully in LDS
    int cur = 0;
    for (int kk = 0; kk < nk; ++kk) {
        if (kk + 1 < nk) stage(cur ^ 1, kk + 1);   // issue next tile first

        bf16x8 af[4], bfr[4];
        const int rA = wr * 64 + (lane & 15);
        const int rB = wc * 64 + (lane & 15);
        const int kb = (lane >> 4) * 4;
#pragma unroll
        for (int m = 0; m < 4; ++m) {
            short4v lo = *(const short4v*)&As[cur][(rA + m * 16) * 32 + kb];
            short4v hi = *(const short4v*)&As[cur][(rA + m * 16) * 32 + kb + 16];
            af[m] = __builtin_bit_cast(bf16x8,
                     __builtin_shufflevector(lo, hi, 0, 1, 2, 3, 4, 5, 6, 7));
        }
#pragma unroll
        for (int n = 0; n < 4; ++n) {
            short4v lo = *(const short4v*)&Bs[cur][(rB + n * 16) * 32 + kb];
            short4v hi = *(const short4v*)&Bs[cur][(rB + n * 16) * 32 + kb + 16];
            bfr[n] = __builtin_bit_cast(bf16x8,
                      __builtin_shufflevector(lo, hi, 0, 1, 2, 3, 4, 5, 6, 7));
        }
#pragma unroll
        for (int m = 0; m < 4; ++m)
#pragma unroll
            for (int n = 0; n < 4; ++n)
                acc[m][n] = __builtin_amdgcn_mfma_f32_16x16x32_bf16(af[m], bfr[n], acc[m][n], 0, 0, 0);

        __syncthreads();           // drains tile kk+1 loads (hidden under compute)
        cur ^= 1;                  // + makes buf[cur] safe to overwrite next iter
    }

    const int row0 = bm * 128 + wr * 64 + ((lane >> 4) * 4);
    const int col0 = bn * 128 + wc * 64 + (lane & 15);
#pragma unroll
    for (int m = 0; m < 4; ++m) {
#pragma unroll
        for (int n = 0; n < 4; ++n) {
            const int col = col0 + n * 16;
#pragma unroll
            for (int r = 0; r < 4; ++r) {
                const int row = row0 + m * 16 + r;
                float v = acc[m][n][r];
                size_t idx = (size_t)row * N + col;
                if (EPI == 0) {
                    ((uint16_t*)outp)[idx] = f2bf(v);
                } else if (EPI == 1) {
                    ((float*)outp)[idx] = v + bias[col] + resid[idx];
                } else {
                    v += bias[col];
                    float ge = 0.5f * v * (1.0f + erff(v * 0.70710678118654752f));
                    ((uint16_t*)outp)[idx] = f2bf(ge);
                }
            }
        }
    }
}

// ---------------- MFMA cross-shaped window attention (swapped QK^T) ----------------
// block = (branch, win, head, qtile); 1 wave. S^T = mfma(K,Q); PV as O^T = mfma(V^T,P^T).
// C/D layout (HW-verified): col = lane&15, row = (lane>>4)*4 + reg.
__global__ __launch_bounds__(64) void attn_mfma(const uint16_t* __restrict__ qkv,
                                                uint16_t* __restrict__ att) {
    __shared__ __align__(16) uint16_t Pl[64 * 40];  // P [64 q][40 halves] (pad 32->40)
    int bid = blockIdx.x;
    const int qtile = bid % 7;  bid /= 7;
    const int head  = bid & 3;  bid >>= 2;
    const int win   = bid & 63; bid >>= 6;
    const int branch = bid;
    const int lane = threadIdx.x;
    const int g  = lane >> 4;
    const int li = lane & 15;
    const int b = win >> 3, wp = win & 7;
    const int ch0 = branch * 128 + head * 32;
    const int base0 = b * 3136;
    const int woff  = wp * 7;
    const int toks1 = base0 + wp * 392;

    auto tokof = [&](int l) -> int {
        if (branch == 0) { int r = l / 7; return base0 + r * 56 + woff + (l - r * 7); }
        return toks1 + l;
    };
    const int tok391 = tokof(391);
    const int q0 = qtile * 64;

    // Q B-frags: n=q=li+16nb, k-slot j -> ch g*8+j
    bf16x8 qf[4];
#pragma unroll
    for (int nb = 0; nb < 4; ++nb) {
        int ql = q0 + nb * 16 + li; if (ql > 391) ql = 391;
        qf[nb] = __builtin_bit_cast(bf16x8,
                 *(const uint4*)(qkv + (size_t)tokof(ql) * 768 + ch0 + g * 8));
    }

    float m_run[4], s_run[4];
    f32x4 oacc[2][4];
#pragma unroll
    for (int nb = 0; nb < 4; ++nb) {
        m_run[nb] = -1e30f; s_run[nb] = 0.f;
        oacc[0][nb] = (f32x4)0.f; oacc[1][nb] = (f32x4)0.f;
    }
    const float scale = 0.17677669529663687f;  // 1/sqrt(32)

    for (int kt = 0; kt < 13; ++kt) {
        const int kbase = kt * 32;
        // K A-frags: m=key=li+16mb, k-slot j -> ch g*8+j
        bf16x8 kf[2];
#pragma unroll
        for (int mb = 0; mb < 2; ++mb) {
            int kl = kbase + mb * 16 + li; if (kl > 391) kl = 391;
            kf[mb] = __builtin_bit_cast(bf16x8,
                     *(const uint4*)(qkv + (size_t)tokof(kl) * 768 + 256 + ch0 + g * 8));
        }
        // V gathers (issued early; A-frags for PV): lane ch=li(+16mb), keys g*8..+7
        uint16_t vg0[8], vg1[8];
        {
            int kl0 = kbase + g * 8;
            int tk, cc = 0;
            if (branch == 0) { int r = kl0 / 7; cc = kl0 - r * 7; tk = base0 + r * 56 + woff + cc; }
            else tk = toks1 + kl0;
#pragma unroll
            for (int j = 0; j < 8; ++j) {
                int t = (kl0 + j > 391) ? tok391 : tk;
                const uint16_t* vp = qkv + (size_t)t * 768 + 512 + ch0 + li;
                vg0[j] = vp[0];
                vg1[j] = vp[16];
                if (branch == 0) { if (++cc == 7) { cc = 0; tk += 50; } else ++tk; }
                else ++tk;
            }
        }
        // S^T[key][q]
        f32x4 sa[2][4] = {};
#pragma unroll
        for (int mb = 0; mb < 2; ++mb)
#pragma unroll
            for (int nb = 0; nb < 4; ++nb)
                sa[mb][nb] = __builtin_amdgcn_mfma_f32_16x16x32_bf16(kf[mb], qf[nb], sa[mb][nb], 0, 0, 0);
#pragma unroll
        for (int mb = 0; mb < 2; ++mb)
#pragma unroll
            for (int nb = 0; nb < 4; ++nb)
#pragma unroll
                for (int r = 0; r < 4; ++r) sa[mb][nb][r] *= scale;
        if (kt == 12) {  // keys valid iff kbase + mb*16 + g*4 + r < 392 -> mb==0 && g<2
#pragma unroll
            for (int nb = 0; nb < 4; ++nb)
#pragma unroll
                for (int r = 0; r < 4; ++r) {
                    if (g >= 2) sa[0][nb][r] = -1e30f;
                    sa[1][nb][r] = -1e30f;
                }
        }
        // online softmax per q-col
#pragma unroll
        for (int nb = 0; nb < 4; ++nb) {
            f32x4 mx = sa[0][nb];
#pragma unroll
            for (int r = 0; r < 4; ++r) mx[r] = fmaxf(mx[r], sa[1][nb][r]);
            float mt = fmaxf(fmaxf(mx[0], mx[1]), fmaxf(mx[2], mx[3]));
            mt = fmaxf(mt, __shfl_xor(mt, 16));
            mt = fmaxf(mt, __shfl_xor(mt, 32));
            float m_new = fmaxf(m_run[nb], mt);
            float corr = __expf(m_run[nb] - m_new);
            m_run[nb] = m_new;
#pragma unroll
            for (int mb = 0; mb < 2; ++mb)
#pragma unroll
                for (int r = 0; r < 4; ++r) oacc[mb][nb][r] *= corr;
            float psum = 0.f;
            uint32_t pk[4];
#pragma unroll
            for (int mb = 0; mb < 2; ++mb) {
                float p0 = __expf(sa[mb][nb][0] - m_new);
                float p1 = __expf(sa[mb][nb][1] - m_new);
                float p2 = __expf(sa[mb][nb][2] - m_new);
                float p3 = __expf(sa[mb][nb][3] - m_new);
                psum += (p0 + p1) + (p2 + p3);
                pk[mb * 2 + 0] = (uint32_t)f2bf(p0) | ((uint32_t)f2bf(p1) << 16);
                pk[mb * 2 + 1] = (uint32_t)f2bf(p2) | ((uint32_t)f2bf(p3) << 16);
            }
            psum += __shfl_xor(psum, 16);
            psum += __shfl_xor(psum, 32);
            s_run[nb] = s_run[nb] * corr + psum;
            // write P[q][key]: q = li+16nb, keys g*4+16mb (+0,1 / +2,3)
            uint32_t* dst = (uint32_t*)&Pl[(li + 16 * nb) * 40];
            dst[g * 2 + 0] = pk[0];
            dst[g * 2 + 1] = pk[1];
            dst[g * 2 + 8] = pk[2];
            dst[g * 2 + 9] = pk[3];
        }
        // PV: O^T += V^T * P^T
        union { uint16_t u[8]; bf16x8 v; } cv0, cv1;
#pragma unroll
        for (int j = 0; j < 8; ++j) { cv0.u[j] = vg0[j]; cv1.u[j] = vg1[j]; }
        bf16x8 vf0 = cv0.v, vf1 = cv1.v;
        bf16x8 pf[4];
#pragma unroll
        for (int nb = 0; nb < 4; ++nb)
            pf[nb] = __builtin_bit_cast(bf16x8,
                     *(const uint4*)&Pl[(li + 16 * nb) * 40 + g * 8]);
#pragma unroll
        for (int nb = 0; nb < 4; ++nb) {
            oacc[0][nb] = __builtin_amdgcn_mfma_f32_16x16x32_bf16(vf0, pf[nb], oacc[0][nb], 0, 0, 0);
            oacc[1][nb] = __builtin_amdgcn_mfma_f32_16x16x32_bf16(vf1, pf[nb], oacc[1][nb], 0, 0, 0);
        }
    }
    // epilogue: O^T row = ch = g*4+r+16mb, col = q = li+16nb
#pragma unroll
    for (int nb = 0; nb < 4; ++nb) {
        int ql = q0 + nb * 16 + li;
        if (ql <= 391) {
            float rn = 1.f / s_run[nb];
            uint16_t* op = att + (size_t)tokof(ql) * 256 + ch0;
#pragma unroll
            for (int mb = 0; mb < 2; ++mb)
#pragma unroll
                for (int r = 0; r < 4; ++r)
                    op[mb * 16 + g * 4 + r] = f2bf(oacc[mb][nb][r] * rn);
        }
    }
}

// ---------------- LePE: att += depthwise 3x3 conv(V) + bias (RMW) ----------------
// Weights staged in LDS; straight-line clamped+masked 9 taps for memory ILP.
__global__ __launch_bounds__(256) void lepe_kernel(const uint16_t* __restrict__ qkv,
                                                   const float* __restrict__ lw0,
                                                   const float* __restrict__ lb0,
                                                   const float* __restrict__ lw1,
                                                   const float* __restrict__ lb1,
                                                   uint16_t* __restrict__ att) {
    __shared__ float wl[9][256];
    __shared__ float bl[256];
    {
        int tid = threadIdx.x;
        for (int i = tid; i < 2304; i += 256) {
            int tap = i >> 8, ch = i & 255;
            wl[tap][ch] = (ch < 128) ? lw0[ch * 9 + tap] : lw1[(ch - 128) * 9 + tap];
        }
        bl[tid] = (tid < 128) ? lb0[tid] : lb1[tid - 128];
    }
    __syncthreads();

    int idx = blockIdx.x * 256 + threadIdx.x;   // 25088*32
    int t = idx >> 5, cg = idx & 31;
    int ch = cg * 8;
    int branch = ch >> 7;
    int b = t / 3136, rem = t - b * 3136, h = rem / 56, w = rem - h * 56;
    int r0, r1, c0, c1;
    if (branch == 0) { r0 = 0; r1 = 55; int wp = w / 7; c0 = wp * 7; c1 = c0 + 6; }
    else             { int hp = h / 7; r0 = hp * 7; r1 = r0 + 6; c0 = 0; c1 = 55; }

    const uint16_t* vbase = qkv + (size_t)b * 3136 * 768 + 512 + ch;
    float acc[8];
    {
        f32x4 b0 = *(const f32x4*)&bl[ch];
        f32x4 b1 = *(const f32x4*)&bl[ch + 4];
#pragma unroll
        for (int d = 0; d < 4; ++d) { acc[d] = b0[d]; acc[d + 4] = b1[d]; }
    }
#pragma unroll
    for (int dy = -1; dy <= 1; ++dy) {
#pragma unroll
        for (int dx = -1; dx <= 1; ++dx) {
            int hh = h + dy, ww = w + dx;
            float mask = (hh >= r0 && hh <= r1 && ww >= c0 && ww <= c1) ? 1.f : 0.f;
            int hc = min(max(hh, r0), r1), wc = min(max(ww, c0), c1);
            uint4 u = *(const uint4*)(vbase + (size_t)(hc * 56 + wc) * 768);
            float vv[8]; unpack8(u, vv);
            const int tap = (dy + 1) * 3 + (dx + 1);
            f32x4 w0 = *(const f32x4*)&wl[tap][ch];
            f32x4 w1 = *(const f32x4*)&wl[tap][ch + 4];
#pragma unroll
            for (int d = 0; d < 4; ++d) {
                acc[d]     += (mask * w0[d]) * vv[d];
                acc[d + 4] += (mask * w1[d]) * vv[d + 4];
            }
        }
    }
    uint16_t* ap = att + (size_t)t * 256 + ch;
    uint4 a = *(const uint4*)ap;
    float av[8]; unpack8(a, av);
    uint16_t ob[8];
#pragma unroll
    for (int d = 0; d < 8; ++d) ob[d] = f2bf(av[d] + acc[d]);
    *(uint4*)ap = *(const uint4*)ob;
}

// ---------------- launch ----------------
extern "C" void kernel_launch(void* const* d_in, const int* in_sizes, int n_in,
                              void* d_out, int out_size, void* d_ws, size_t ws_size,
                              hipStream_t stream) {
    const float* x      = (const float*)d_in[0];
    const float* g1     = (const float*)d_in[1];
    const float* be1    = (const float*)d_in[2];
    const float* w_qkv  = (const float*)d_in[3];
    const float* lw0    = (const float*)d_in[4];
    const float* lb0    = (const float*)d_in[5];
    const float* lw1    = (const float*)d_in[6];
    const float* lb1    = (const float*)d_in[7];
    const float* w_proj = (const float*)d_in[8];
    const float* b_proj = (const float*)d_in[9];
    const float* g2     = (const float*)d_in[10];
    const float* be2    = (const float*)d_in[11];
    const float* w_fc1  = (const float*)d_in[12];
    const float* b_fc1  = (const float*)d_in[13];
    const float* w_fc2  = (const float*)d_in[14];
    const float* b_fc2  = (const float*)d_in[15];
    float* out = (float*)d_out;

    char* p = (char*)d_ws;
    auto carve = [&](size_t bytes) -> char* {
        char* q = p; p += (bytes + 255) & ~(size_t)255; return q;
    };
    uint16_t* lnb    = (uint16_t*)carve((size_t)25088 * 256 * 2);   // ln1 then ln2
    uint16_t* qkvh   = (uint16_t*)carve((size_t)25088 * 1024 * 2);  // qkv then h
    uint16_t* attb   = (uint16_t*)carve((size_t)25088 * 256 * 2);
    float*    x1     = (float*)   carve((size_t)25088 * 256 * 4);
    uint16_t* wqkvT  = (uint16_t*)carve((size_t)768 * 256 * 2);
    uint16_t* wprojT = (uint16_t*)carve((size_t)256 * 256 * 2);
    uint16_t* wfc1T  = (uint16_t*)carve((size_t)1024 * 256 * 2);
    uint16_t* wfc2T  = (uint16_t*)carve((size_t)256 * 1024 * 2);

    wprep<<<768,  256, 0, stream>>>(w_qkv,  wqkvT,  256, 768);
    wprep<<<256,  256, 0, stream>>>(w_proj, wprojT, 256, 256);
    wprep<<<1024, 256, 0, stream>>>(w_fc1,  wfc1T,  256, 1024);
    wprep<<<1024, 256, 0, stream>>>(w_fc2,  wfc2T,  1024, 256);

    ln_kernel<<<6272, 256, 0, stream>>>(x, g1, be1, lnb);
    gemm_bt<0><<<dim3(196, 6), 256, 0, stream>>>(lnb, wqkvT, 25088, 768, 256,
                                                 nullptr, nullptr, qkvh);
    attn_mfma<<<3584, 64, 0, stream>>>(qkvh, attb);
    lepe_kernel<<<3136, 256, 0, stream>>>(qkvh, lw0, lb0, lw1, lb1, attb);
    gemm_bt<1><<<dim3(196, 2), 256, 0, stream>>>(attb, wprojT, 25088, 256, 256,
                                                 b_proj, x, x1);
    ln_kernel<<<6272, 256, 0, stream>>>(x1, g2, be2, lnb);
    gemm_bt<2><<<dim3(196, 8), 256, 0, stream>>>(lnb, wfc1T, 25088, 1024, 256,
                                                 b_fc1, nullptr, qkvh);
    gemm_bt<1><<<dim3(196, 2), 256, 0, stream>>>(qkvh, wfc2T, 25088, 256, 1024,
                                                 b_fc2, x1, out);
}

// Round 7
// 310.213 us; speedup vs baseline: 2.2206x; 1.2595x over previous
//
#include <hip/hip_runtime.h>
#include <stdint.h>

typedef __attribute__((ext_vector_type(4))) float  f32x4;
typedef __attribute__((ext_vector_type(8))) __bf16 bf16x8;

#define DEVI static __device__ __forceinline__

DEVI float bf2f_lo(uint32_t u) { union { uint32_t i; float f; } v; v.i = u << 16;          return v.f; }
DEVI float bf2f_hi(uint32_t u) { union { uint32_t i; float f; } v; v.i = u & 0xffff0000u;  return v.f; }
DEVI uint16_t f2bf(float f) {
    union { float f; uint32_t i; } v; v.f = f;
    uint32_t r = v.i + 0x7fffu + ((v.i >> 16) & 1u);
    return (uint16_t)(r >> 16);
}
DEVI void unpack8(uint4 u, float* f) {
    f[0] = bf2f_lo(u.x); f[1] = bf2f_hi(u.x);
    f[2] = bf2f_lo(u.y); f[3] = bf2f_hi(u.y);
    f[4] = bf2f_lo(u.z); f[5] = bf2f_hi(u.z);
    f[6] = bf2f_lo(u.w); f[7] = bf2f_hi(u.w);
}
DEVI void gload_lds16(const uint16_t* gp, uint16_t* lp) {
    __builtin_amdgcn_global_load_lds(
        (const __attribute__((address_space(1))) uint32_t*)gp,
        (__attribute__((address_space(3))) uint32_t*)lp, 16, 0, 0);
}

// ---------------- weight prep: fp32 [K][N] -> bf16 [N][K] ----------------
__global__ __launch_bounds__(256) void wprep(const float* __restrict__ w,
                                             uint16_t* __restrict__ wt, int K, int N) {
    int idx = blockIdx.x * 256 + threadIdx.x;
    if (idx >= K * N) return;
    int k = idx / N, n = idx - k * N;
    wt[(size_t)n * K + k] = f2bf(w[idx]);
}

// ---------------- LayerNorm over C=256, write bf16 ----------------
__global__ __launch_bounds__(256) void ln_kernel(const float* __restrict__ x,
                                                 const float* __restrict__ g,
                                                 const float* __restrict__ be,
                                                 uint16_t* __restrict__ y) {
    int row  = blockIdx.x * 4 + (threadIdx.x >> 6);
    int lane = threadIdx.x & 63;
    const float* xr = x + (size_t)row * 256 + lane * 4;
    f32x4 v = *(const f32x4*)xr;
    float s  = v[0] + v[1] + v[2] + v[3];
    float s2 = v[0]*v[0] + v[1]*v[1] + v[2]*v[2] + v[3]*v[3];
#pragma unroll
    for (int off = 32; off > 0; off >>= 1) {
        s  += __shfl_xor(s, off);
        s2 += __shfl_xor(s2, off);
    }
    float mean = s * (1.f / 256.f);
    float var  = s2 * (1.f / 256.f) - mean * mean;
    float rs   = rsqrtf(var + 1e-5f);
    f32x4 gv = *(const f32x4*)(g  + lane * 4);
    f32x4 bv = *(const f32x4*)(be + lane * 4);
    uint64_t pk = 0;
#pragma unroll
    for (int j = 0; j < 4; ++j) {
        uint64_t b = f2bf((v[j] - mean) * rs * gv[j] + bv[j]);
        pk |= b << (16 * j);
    }
    *(uint64_t*)(y + (size_t)row * 256 + lane * 4) = pk;
}

// ---------------- GEMM: A[M][K] bf16  x  Bt[N][K] bf16 -> epilogue ----------------
// 2-phase double-buffer (prefetch next tile before compute, one __syncthreads/tile).
// T2 LDS swizzle (16B-granular XOR, both-sides): LDS slot (row,c) holds global chunk
// c ^ h(row), h(row)=(row^(row>>2))&3.  Staged via inverse-swizzled global source
// (linear gload_lds dest); fragments read as single ds_read_b128 at chunk g^h(row).
// Read conflict: 2-way (free).  k-convention (contiguous block g) identical for A and
// B, so the lane->k mapping cancels in the MFMA contraction.
// EPI 0: store bf16 raw;  1: +bias +resid -> fp32;  2: +bias, exact GELU -> bf16
template <int EPI>
__global__ __launch_bounds__(256) void gemm_bt(const uint16_t* __restrict__ A,
                                               const uint16_t* __restrict__ Bt,
                                               int M, int N, int K,
                                               const float* __restrict__ bias,
                                               const float* __restrict__ resid,
                                               void* __restrict__ outp) {
    __shared__ __align__(16) uint16_t As[2][128 * 32];
    __shared__ __align__(16) uint16_t Bs[2][128 * 32];
    const int tid  = threadIdx.x;
    const int lane = tid & 63;
    const int w    = tid >> 6;
    const int wr   = w >> 1, wc = w & 1;
    const int bm = blockIdx.x, bn = blockIdx.y;
    f32x4 acc[4][4] = {};
    const int nk = K >> 5;
    const int wb = w * 512;            // wave-uniform LDS base (halves)

    // staging source: thread slot (row = tid>>2, chunk = tid&3); fetch global chunk
    // (tid&3) ^ h(row) so LDS slot c ends up holding global chunk c ^ h(row).
    const int srow = tid >> 2;
    const int hwr  = (srow ^ (srow >> 2)) & 3;           // h(row); h(row+64)==h(row)
    const size_t ao0 = (size_t)srow * K + (size_t)(((tid & 3) ^ hwr) * 8);
    const size_t ao1 = ao0 + (size_t)64 * K;

    const uint16_t* Abase = A  + (size_t)bm * 128 * K;
    const uint16_t* Bbase = Bt + (size_t)bn * 128 * K;

    auto stage = [&](int buf, int kk) {
        const uint16_t* Ab = Abase + kk * 32;
        const uint16_t* Bb = Bbase + kk * 32;
        gload_lds16(Ab + ao0, &As[buf][wb]);
        gload_lds16(Ab + ao1, &As[buf][wb + 2048]);
        gload_lds16(Bb + ao0, &Bs[buf][wb]);
        gload_lds16(Bb + ao1, &Bs[buf][wb + 2048]);
    };

    stage(0, 0);
    __syncthreads();               // tile 0 fully in LDS
    int cur = 0;

    const int li = lane & 15;
    const int rA = wr * 64 + li;
    const int rB = wc * 64 + li;
    // read chunk: g ^ h(row); h(rA+16m) == h(li) since wr*64, m*16 vanish mod the h bits
    const int kx = ((lane >> 4) ^ ((li ^ (li >> 2)) & 3)) * 8;

    for (int kk = 0; kk < nk; ++kk) {
        if (kk + 1 < nk) stage(cur ^ 1, kk + 1);   // issue next tile first

        bf16x8 af[4], bfr[4];
#pragma unroll
        for (int m = 0; m < 4; ++m)
            af[m] = __builtin_bit_cast(bf16x8,
                     *(const uint4*)&As[cur][(rA + m * 16) * 32 + kx]);
#pragma unroll
        for (int n = 0; n < 4; ++n)
            bfr[n] = __builtin_bit_cast(bf16x8,
                      *(const uint4*)&Bs[cur][(rB + n * 16) * 32 + kx]);
#pragma unroll
        for (int m = 0; m < 4; ++m)
#pragma unroll
            for (int n = 0; n < 4; ++n)
                acc[m][n] = __builtin_amdgcn_mfma_f32_16x16x32_bf16(af[m], bfr[n], acc[m][n], 0, 0, 0);

        __syncthreads();           // drains tile kk+1 loads (hidden under compute)
        cur ^= 1;                  // + makes buf[cur] safe to overwrite next iter
    }

    const int row0 = bm * 128 + wr * 64 + ((lane >> 4) * 4);
    const int col0 = bn * 128 + wc * 64 + li;
#pragma unroll
    for (int m = 0; m < 4; ++m) {
#pragma unroll
        for (int n = 0; n < 4; ++n) {
            const int col = col0 + n * 16;
#pragma unroll
            for (int r = 0; r < 4; ++r) {
                const int row = row0 + m * 16 + r;
                float v = acc[m][n][r];
                size_t idx = (size_t)row * N + col;
                if (EPI == 0) {
                    ((uint16_t*)outp)[idx] = f2bf(v);
                } else if (EPI == 1) {
                    ((float*)outp)[idx] = v + bias[col] + resid[idx];
                } else {
                    v += bias[col];
                    float ge = 0.5f * v * (1.0f + erff(v * 0.70710678118654752f));
                    ((uint16_t*)outp)[idx] = f2bf(ge);
                }
            }
        }
    }
}

// ---------------- MFMA cross-shaped window attention (swapped QK^T) ----------------
// block = (branch, win, head, qtile); 1 wave. S^T = mfma(K,Q); PV as O^T = mfma(V^T,P^T).
// C/D layout (HW-verified): col = lane&15, row = (lane>>4)*4 + reg.
__global__ __launch_bounds__(64) void attn_mfma(const uint16_t* __restrict__ qkv,
                                                uint16_t* __restrict__ att) {
    __shared__ __align__(16) uint16_t Pl[64 * 40];  // P [64 q][40 halves] (pad 32->40)
    int bid = blockIdx.x;
    const int qtile = bid % 7;  bid /= 7;
    const int head  = bid & 3;  bid >>= 2;
    const int win   = bid & 63; bid >>= 6;
    const int branch = bid;
    const int lane = threadIdx.x;
    const int g  = lane >> 4;
    const int li = lane & 15;
    const int b = win >> 3, wp = win & 7;
    const int ch0 = branch * 128 + head * 32;
    const int base0 = b * 3136;
    const int woff  = wp * 7;
    const int toks1 = base0 + wp * 392;

    auto tokof = [&](int l) -> int {
        if (branch == 0) { int r = l / 7; return base0 + r * 56 + woff + (l - r * 7); }
        return toks1 + l;
    };
    const int tok391 = tokof(391);
    const int q0 = qtile * 64;

    // Q B-frags: n=q=li+16nb, k-slot j -> ch g*8+j
    bf16x8 qf[4];
#pragma unroll
    for (int nb = 0; nb < 4; ++nb) {
        int ql = q0 + nb * 16 + li; if (ql > 391) ql = 391;
        qf[nb] = __builtin_bit_cast(bf16x8,
                 *(const uint4*)(qkv + (size_t)tokof(ql) * 768 + ch0 + g * 8));
    }

    float m_run[4], s_run[4];
    f32x4 oacc[2][4];
#pragma unroll
    for (int nb = 0; nb < 4; ++nb) {
        m_run[nb] = -1e30f; s_run[nb] = 0.f;
        oacc[0][nb] = (f32x4)0.f; oacc[1][nb] = (f32x4)0.f;
    }
    const float scale = 0.17677669529663687f;  // 1/sqrt(32)

    for (int kt = 0; kt < 13; ++kt) {
        const int kbase = kt * 32;
        // K A-frags: m=key=li+16mb, k-slot j -> ch g*8+j
        bf16x8 kf[2];
#pragma unroll
        for (int mb = 0; mb < 2; ++mb) {
            int kl = kbase + mb * 16 + li; if (kl > 391) kl = 391;
            kf[mb] = __builtin_bit_cast(bf16x8,
                     *(const uint4*)(qkv + (size_t)tokof(kl) * 768 + 256 + ch0 + g * 8));
        }
        // V gathers (issued early; A-frags for PV): lane ch=li(+16mb), keys g*8..+7
        uint16_t vg0[8], vg1[8];
        {
            int kl0 = kbase + g * 8;
            int tk, cc = 0;
            if (branch == 0) { int r = kl0 / 7; cc = kl0 - r * 7; tk = base0 + r * 56 + woff + cc; }
            else tk = toks1 + kl0;
#pragma unroll
            for (int j = 0; j < 8; ++j) {
                int t = (kl0 + j > 391) ? tok391 : tk;
                const uint16_t* vp = qkv + (size_t)t * 768 + 512 + ch0 + li;
                vg0[j] = vp[0];
                vg1[j] = vp[16];
                if (branch == 0) { if (++cc == 7) { cc = 0; tk += 50; } else ++tk; }
                else ++tk;
            }
        }
        // S^T[key][q]
        f32x4 sa[2][4] = {};
#pragma unroll
        for (int mb = 0; mb < 2; ++mb)
#pragma unroll
            for (int nb = 0; nb < 4; ++nb)
                sa[mb][nb] = __builtin_amdgcn_mfma_f32_16x16x32_bf16(kf[mb], qf[nb], sa[mb][nb], 0, 0, 0);
#pragma unroll
        for (int mb = 0; mb < 2; ++mb)
#pragma unroll
            for (int nb = 0; nb < 4; ++nb)
#pragma unroll
                for (int r = 0; r < 4; ++r) sa[mb][nb][r] *= scale;
        if (kt == 12) {  // keys valid iff kbase + mb*16 + g*4 + r < 392 -> mb==0 && g<2
#pragma unroll
            for (int nb = 0; nb < 4; ++nb)
#pragma unroll
                for (int r = 0; r < 4; ++r) {
                    if (g >= 2) sa[0][nb][r] = -1e30f;
                    sa[1][nb][r] = -1e30f;
                }
        }
        // online softmax per q-col
#pragma unroll
        for (int nb = 0; nb < 4; ++nb) {
            f32x4 mx = sa[0][nb];
#pragma unroll
            for (int r = 0; r < 4; ++r) mx[r] = fmaxf(mx[r], sa[1][nb][r]);
            float mt = fmaxf(fmaxf(mx[0], mx[1]), fmaxf(mx[2], mx[3]));
            mt = fmaxf(mt, __shfl_xor(mt, 16));
            mt = fmaxf(mt, __shfl_xor(mt, 32));
            float m_new = fmaxf(m_run[nb], mt);
            float corr = __expf(m_run[nb] - m_new);
            m_run[nb] = m_new;
#pragma unroll
            for (int mb = 0; mb < 2; ++mb)
#pragma unroll
                for (int r = 0; r < 4; ++r) oacc[mb][nb][r] *= corr;
            float psum = 0.f;
            uint32_t pk[4];
#pragma unroll
            for (int mb = 0; mb < 2; ++mb) {
                float p0 = __expf(sa[mb][nb][0] - m_new);
                float p1 = __expf(sa[mb][nb][1] - m_new);
                float p2 = __expf(sa[mb][nb][2] - m_new);
                float p3 = __expf(sa[mb][nb][3] - m_new);
                psum += (p0 + p1) + (p2 + p3);
                pk[mb * 2 + 0] = (uint32_t)f2bf(p0) | ((uint32_t)f2bf(p1) << 16);
                pk[mb * 2 + 1] = (uint32_t)f2bf(p2) | ((uint32_t)f2bf(p3) << 16);
            }
            psum += __shfl_xor(psum, 16);
            psum += __shfl_xor(psum, 32);
            s_run[nb] = s_run[nb] * corr + psum;
            // write P[q][key]: q = li+16nb, keys g*4+16mb (+0,1 / +2,3)
            uint32_t* dst = (uint32_t*)&Pl[(li + 16 * nb) * 40];
            dst[g * 2 + 0] = pk[0];
            dst[g * 2 + 1] = pk[1];
            dst[g * 2 + 8] = pk[2];
            dst[g * 2 + 9] = pk[3];
        }
        // PV: O^T += V^T * P^T
        union { uint16_t u[8]; bf16x8 v; } cv0, cv1;
#pragma unroll
        for (int j = 0; j < 8; ++j) { cv0.u[j] = vg0[j]; cv1.u[j] = vg1[j]; }
        bf16x8 vf0 = cv0.v, vf1 = cv1.v;
        bf16x8 pf[4];
#pragma unroll
        for (int nb = 0; nb < 4; ++nb)
            pf[nb] = __builtin_bit_cast(bf16x8,
                     *(const uint4*)&Pl[(li + 16 * nb) * 40 + g * 8]);
#pragma unroll
        for (int nb = 0; nb < 4; ++nb) {
            oacc[0][nb] = __builtin_amdgcn_mfma_f32_16x16x32_bf16(vf0, pf[nb], oacc[0][nb], 0, 0, 0);
            oacc[1][nb] = __builtin_amdgcn_mfma_f32_16x16x32_bf16(vf1, pf[nb], oacc[1][nb], 0, 0, 0);
        }
    }
    // epilogue: O^T row = ch = g*4+r+16mb, col = q = li+16nb
#pragma unroll
    for (int nb = 0; nb < 4; ++nb) {
        int ql = q0 + nb * 16 + li;
        if (ql <= 391) {
            float rn = 1.f / s_run[nb];
            uint16_t* op = att + (size_t)tokof(ql) * 256 + ch0;
#pragma unroll
            for (int mb = 0; mb < 2; ++mb)
#pragma unroll
                for (int r = 0; r < 4; ++r)
                    op[mb * 16 + g * 4 + r] = f2bf(oacc[mb][nb][r] * rn);
        }
    }
}

// ---------------- LePE: att += depthwise 3x3 conv(V) + bias (RMW) ----------------
// Weights staged in LDS; straight-line clamped+masked 9 taps for memory ILP.
__global__ __launch_bounds__(256) void lepe_kernel(const uint16_t* __restrict__ qkv,
                                                   const float* __restrict__ lw0,
                                                   const float* __restrict__ lb0,
                                                   const float* __restrict__ lw1,
                                                   const float* __restrict__ lb1,
                                                   uint16_t* __restrict__ att) {
    __shared__ float wl[9][256];
    __shared__ float bl[256];
    {
        int tid = threadIdx.x;
        for (int i = tid; i < 2304; i += 256) {
            int tap = i >> 8, ch = i & 255;
            wl[tap][ch] = (ch < 128) ? lw0[ch * 9 + tap] : lw1[(ch - 128) * 9 + tap];
        }
        bl[tid] = (tid < 128) ? lb0[tid] : lb1[tid - 128];
    }
    __syncthreads();

    int idx = blockIdx.x * 256 + threadIdx.x;   // 25088*32
    int t = idx >> 5, cg = idx & 31;
    int ch = cg * 8;
    int branch = ch >> 7;
    int b = t / 3136, rem = t - b * 3136, h = rem / 56, w = rem - h * 56;
    int r0, r1, c0, c1;
    if (branch == 0) { r0 = 0; r1 = 55; int wp = w / 7; c0 = wp * 7; c1 = c0 + 6; }
    else             { int hp = h / 7; r0 = hp * 7; r1 = r0 + 6; c0 = 0; c1 = 55; }

    const uint16_t* vbase = qkv + (size_t)b * 3136 * 768 + 512 + ch;
    float acc[8];
    {
        f32x4 b0 = *(const f32x4*)&bl[ch];
        f32x4 b1 = *(const f32x4*)&bl[ch + 4];
#pragma unroll
        for (int d = 0; d < 4; ++d) { acc[d] = b0[d]; acc[d + 4] = b1[d]; }
    }
#pragma unroll
    for (int dy = -1; dy <= 1; ++dy) {
#pragma unroll
        for (int dx = -1; dx <= 1; ++dx) {
            int hh = h + dy, ww = w + dx;
            float mask = (hh >= r0 && hh <= r1 && ww >= c0 && ww <= c1) ? 1.f : 0.f;
            int hc = min(max(hh, r0), r1), wc = min(max(ww, c0), c1);
            uint4 u = *(const uint4*)(vbase + (size_t)(hc * 56 + wc) * 768);
            float vv[8]; unpack8(u, vv);
            const int tap = (dy + 1) * 3 + (dx + 1);
            f32x4 w0 = *(const f32x4*)&wl[tap][ch];
            f32x4 w1 = *(const f32x4*)&wl[tap][ch + 4];
#pragma unroll
            for (int d = 0; d < 4; ++d) {
                acc[d]     += (mask * w0[d]) * vv[d];
                acc[d + 4] += (mask * w1[d]) * vv[d + 4];
            }
        }
    }
    uint16_t* ap = att + (size_t)t * 256 + ch;
    uint4 a = *(const uint4*)ap;
    float av[8]; unpack8(a, av);
    uint16_t ob[8];
#pragma unroll
    for (int d = 0; d < 8; ++d) ob[d] = f2bf(av[d] + acc[d]);
    *(uint4*)ap = *(const uint4*)ob;
}

// ---------------- launch ----------------
extern "C" void kernel_launch(void* const* d_in, const int* in_sizes, int n_in,
                              void* d_out, int out_size, void* d_ws, size_t ws_size,
                              hipStream_t stream) {
    const float* x      = (const float*)d_in[0];
    const float* g1     = (const float*)d_in[1];
    const float* be1    = (const float*)d_in[2];
    const float* w_qkv  = (const float*)d_in[3];
    const float* lw0    = (const float*)d_in[4];
    const float* lb0    = (const float*)d_in[5];
    const float* lw1    = (const float*)d_in[6];
    const float* lb1    = (const float*)d_in[7];
    const float* w_proj = (const float*)d_in[8];
    const float* b_proj = (const float*)d_in[9];
    const float* g2     = (const float*)d_in[10];
    const float* be2    = (const float*)d_in[11];
    const float* w_fc1  = (const float*)d_in[12];
    const float* b_fc1  = (const float*)d_in[13];
    const float* w_fc2  = (const float*)d_in[14];
    const float* b_fc2  = (const float*)d_in[15];
    float* out = (float*)d_out;

    char* p = (char*)d_ws;
    auto carve = [&](size_t bytes) -> char* {
        char* q = p; p += (bytes + 255) & ~(size_t)255; return q;
    };
    uint16_t* lnb    = (uint16_t*)carve((size_t)25088 * 256 * 2);   // ln1 then ln2
    uint16_t* qkvh   = (uint16_t*)carve((size_t)25088 * 1024 * 2);  // qkv then h
    uint16_t* attb   = (uint16_t*)carve((size_t)25088 * 256 * 2);
    float*    x1     = (float*)   carve((size_t)25088 * 256 * 4);
    uint16_t* wqkvT  = (uint16_t*)carve((size_t)768 * 256 * 2);
    uint16_t* wprojT = (uint16_t*)carve((size_t)256 * 256 * 2);
    uint16_t* wfc1T  = (uint16_t*)carve((size_t)1024 * 256 * 2);
    uint16_t* wfc2T  = (uint16_t*)carve((size_t)256 * 1024 * 2);

    wprep<<<768,  256, 0, stream>>>(w_qkv,  wqkvT,  256, 768);
    wprep<<<256,  256, 0, stream>>>(w_proj, wprojT, 256, 256);
    wprep<<<1024, 256, 0, stream>>>(w_fc1,  wfc1T,  256, 1024);
    wprep<<<1024, 256, 0, stream>>>(w_fc2,  wfc2T,  1024, 256);

    ln_kernel<<<6272, 256, 0, stream>>>(x, g1, be1, lnb);
    gemm_bt<0><<<dim3(196, 6), 256, 0, stream>>>(lnb, wqkvT, 25088, 768, 256,
                                                 nullptr, nullptr, qkvh);
    attn_mfma<<<3584, 64, 0, stream>>>(qkvh, attb);
    lepe_kernel<<<3136, 256, 0, stream>>>(qkvh, lw0, lb0, lw1, lb1, attb);
    gemm_bt<1><<<dim3(196, 2), 256, 0, stream>>>(attb, wprojT, 25088, 256, 256,
                                                 b_proj, x, x1);
    ln_kernel<<<6272, 256, 0, stream>>>(x1, g2, be2, lnb);
    gemm_bt<2><<<dim3(196, 8), 256, 0, stream>>>(lnb, wfc1T, 25088, 1024, 256,
                                                 b_fc1, nullptr, qkvh);
    gemm_bt<1><<<dim3(196, 2), 256, 0, stream>>>(qkvh, wfc2T, 25088, 256, 1024,
                                                 b_fc2, x1, out);
}